// Round 6
// baseline (299.540 us; speedup 1.0000x reference)
//
#include <hip/hip_runtime.h>
#include <hip/hip_bf16.h>

#define DEVI __device__ __forceinline__

typedef __bf16 bf16_t;
typedef __bf16 bf16x8 __attribute__((ext_vector_type(8)));
typedef float  f32x4  __attribute__((ext_vector_type(4)));
typedef float  f32x16 __attribute__((ext_vector_type(16)));
typedef unsigned short u16x4 __attribute__((ext_vector_type(4)));
typedef unsigned int   u32x4 __attribute__((ext_vector_type(4)));

typedef __attribute__((address_space(1))) unsigned int gas_u32;
typedef __attribute__((address_space(3))) unsigned int las_u32;

#define LOG2E 1.4426950408889634f

DEVI void gload16(const void* g, void* l) {
  __builtin_amdgcn_global_load_lds((gas_u32*)g, (las_u32*)l, 16, 0, 0);
}

DEVI unsigned short bf16bits(float f) {
  bf16_t b = (bf16_t)f;
  return __builtin_bit_cast(unsigned short, b);
}

DEVI unsigned pk2(float a, float b) {
  return ((unsigned)bf16bits(b) << 16) | (unsigned)bf16bits(a);
}

DEVI unsigned short quant1(float wv, double s) {
  double tq = (double)wv / s;
  tq = fmin(fmax(tq, -1.0), 1.0);
  return __builtin_bit_cast(unsigned short, (bf16_t)(float)rint(tq));
}

// ---------- fused |w| partial sums (both weights, deterministic) ----------
__global__ __launch_bounds__(256) void k_abssum2(const float* __restrict__ wq,
                                                 const float* __restrict__ wp,
                                                 double* __restrict__ partials) {
  __shared__ double sm[256];
  const int t = threadIdx.x, bid = blockIdx.x;
  const float* __restrict__ w = (bid < 256) ? wq : wp;
  const int n = (bid < 256) ? 1769472 : 589824;
  const int b0 = bid & 255;
  double acc = 0.0;
  for (int i = b0 * 256 + t; i < n; i += 65536)
    acc += (double)fabsf(w[i]);
  sm[t] = acc;
  __syncthreads();
  #pragma unroll
  for (int s = 128; s > 0; s >>= 1) {
    if (t < s) sm[t] += sm[t + s];
    __syncthreads();
  }
  if (t == 0) partials[bid] = sm[0];
}

__global__ __launch_bounds__(256) void k_reduce2(const double* __restrict__ partials,
                                                 double* __restrict__ outs) {
  __shared__ double sm[256];
  const int t = threadIdx.x;
  sm[t] = partials[blockIdx.x * 256 + t];
  __syncthreads();
  #pragma unroll
  for (int s = 128; s > 0; s >>= 1) {
    if (t < s) sm[t] += sm[t + s];
    __syncthreads();
  }
  if (t == 0) outs[blockIdx.x] = sm[0];
}

// ---------- fused prep: quantize both weights + x->bf16, float4-vectorized ----------
__global__ __launch_bounds__(256) void k_prep(
    const float* __restrict__ wq, const float* __restrict__ wp,
    const float* __restrict__ x, const double* __restrict__ scl,
    bf16_t* __restrict__ wqs, bf16_t* __restrict__ wps, bf16_t* __restrict__ xbf) {
  const int bid = blockIdx.x, t = threadIdx.x;
  if (bid < 1728) {
    const double s = scl[0] * (1.0 / 1769472.0) + 1e-5;
    const int i = bid * 256 + t;
    const float4 v = ((const float4*)wq)[i];
    u16x4 o = { quant1(v.x, s), quant1(v.y, s), quant1(v.z, s), quant1(v.w, s) };
    ((u16x4*)wqs)[i] = o;
  } else if (bid < 2304) {
    const double s = scl[1] * (1.0 / 589824.0) + 1e-5;
    const int i = (bid - 1728) * 256 + t;
    const float4 v = ((const float4*)wp)[i];
    u16x4 o = { quant1(v.x, s), quant1(v.y, s), quant1(v.z, s), quant1(v.w, s) };
    ((u16x4*)wps)[i] = o;
  } else {
    const int i = (bid - 2304) * 256 + t;
    const float4 v = ((const float4*)x)[i];
    u16x4 pk = { bf16bits(v.x), bf16bits(v.y), bf16bits(v.z), bf16bits(v.w) };
    ((u16x4*)xbf)[i] = pk;
  }
}

// ---------- pipelined GEMM (unchanged from round 5, verified) ----------
// 256x128 tile, BK=64, 8 waves (4Mx2N); 3 LDS slots; counted vmcnt(6)/K-tile.
template<int MODE>
__global__ __launch_bounds__(512, 2) void k_gemm(
    const bf16_t* __restrict__ A, const bf16_t* __restrict__ Bw,
    const double* __restrict__ sumptr, double invn,
    bf16_t* __restrict__ Qb, bf16_t* __restrict__ Kb, bf16_t* __restrict__ VTb,
    const float* __restrict__ bias, float* __restrict__ Out,
    int nxblk)
{
  __shared__ __align__(16) char lds[147456];
  const int t = threadIdx.x, l = t & 63, w = t >> 6;

  const int nblk = nxblk * 64;
  const int flat = blockIdx.y * nxblk + blockIdx.x;
  const int per = nblk >> 3;
  const int swz = (flat & 7) * per + (flat >> 3);
  const int m0 = (swz / nxblk) * 256, n0 = (swz % nxblk) * 128;

  const int wm = w >> 1, wn = w & 1;
  const int srow = l >> 3, scol = (l & 7) * 8;
  const int lq = l & 15, lh = l >> 4;
  const int gcol = scol ^ (srow * 8);

  auto sA = [&](int slot, int kts, int ha, int c) {
    const int row = ha * 128 + (c * 8 + w) * 8 + srow;
    gload16(A + (size_t)(m0 + row) * 768 + kts * 64 + gcol,
            lds + slot * 49152 + ha * 16384 + (c * 8 + w) * 1024);
  };
  auto sB = [&](int slot, int kts, int c) {
    const int row = (c * 8 + w) * 8 + srow;
    gload16(Bw + (size_t)(n0 + row) * 768 + kts * 64 + gcol,
            lds + slot * 49152 + 32768 + (c * 8 + w) * 1024);
  };

  f32x4 acc[4][4] = {};

  sA(0, 0, 0, 0); sA(0, 0, 0, 1); sA(0, 0, 1, 0); sA(0, 0, 1, 1);
  sB(0, 0, 0);    sB(0, 0, 1);
  sA(1, 1, 0, 0); sA(1, 1, 0, 1); sA(1, 1, 1, 0); sA(1, 1, 1, 1);
  sB(1, 1, 0);    sB(1, 1, 1);
  asm volatile("s_waitcnt vmcnt(6)" ::: "memory");
  asm volatile("s_barrier" ::: "memory");

  #pragma unroll
  for (int kt = 0; kt < 12; ++kt) {
    const char* cA = lds + (kt % 3) * 49152;
    const char* cB = cA + 32768;
    const int st3 = (kt + 2) % 3;
    const bool stg = (kt < 10);

    {
      bf16x8 af[4], bf[4];
      #pragma unroll
      for (int i = 0; i < 4; ++i) {
        const int row = wm * 64 + i * 16 + lq;
        af[i] = *(const bf16x8*)(cA + row * 128 + ((lh * 16) ^ ((row & 7) << 4)));
      }
      #pragma unroll
      for (int j = 0; j < 4; ++j) {
        const int row = wn * 64 + j * 16 + lq;
        bf[j] = *(const bf16x8*)(cB + row * 128 + ((lh * 16) ^ ((row & 7) << 4)));
      }
      if (stg) { sA(st3, kt + 2, 0, 0); sA(st3, kt + 2, 0, 1); sB(st3, kt + 2, 0); }
      asm volatile("s_barrier" ::: "memory");
      __builtin_amdgcn_s_setprio(1);
      #pragma unroll
      for (int i = 0; i < 4; ++i)
        #pragma unroll
        for (int j = 0; j < 4; ++j)
          acc[i][j] = __builtin_amdgcn_mfma_f32_16x16x32_bf16(af[i], bf[j], acc[i][j], 0, 0, 0);
      __builtin_amdgcn_s_setprio(0);
      asm volatile("s_barrier" ::: "memory");
    }
    {
      bf16x8 af[4], bf[4];
      #pragma unroll
      for (int i = 0; i < 4; ++i) {
        const int row = wm * 64 + i * 16 + lq;
        af[i] = *(const bf16x8*)(cA + row * 128 + ((64 + lh * 16) ^ ((row & 7) << 4)));
      }
      #pragma unroll
      for (int j = 0; j < 4; ++j) {
        const int row = wn * 64 + j * 16 + lq;
        bf[j] = *(const bf16x8*)(cB + row * 128 + ((64 + lh * 16) ^ ((row & 7) << 4)));
      }
      if (stg) { sA(st3, kt + 2, 1, 0); sA(st3, kt + 2, 1, 1); sB(st3, kt + 2, 1); }
      asm volatile("s_barrier" ::: "memory");
      __builtin_amdgcn_s_setprio(1);
      #pragma unroll
      for (int i = 0; i < 4; ++i)
        #pragma unroll
        for (int j = 0; j < 4; ++j)
          acc[i][j] = __builtin_amdgcn_mfma_f32_16x16x32_bf16(af[i], bf[j], acc[i][j], 0, 0, 0);
      __builtin_amdgcn_s_setprio(0);
      if (stg) asm volatile("s_waitcnt vmcnt(6)" ::: "memory");
      else     asm volatile("s_waitcnt vmcnt(0)" ::: "memory");
      asm volatile("s_barrier" ::: "memory");
    }
  }

  const float s = (float)((*sumptr) * invn);
  char* st = lds + w * 8192;

  const int mrow0 = m0 + wm * 64;
  const int b = mrow0 >> 10, nbase = mrow0 & 1023;

  if (MODE == 0) {
    const int d0 = n0 + wn * 64;
    const int which = d0 / 768;
    const int hh = (d0 >> 6) % 12;
    if (which == 2) {
      #pragma unroll
      for (int j = 0; j < 4; ++j)
        #pragma unroll
        for (int i = 0; i < 4; ++i)
          #pragma unroll
          for (int r = 0; r < 4; ++r) {
            const int rowd = j * 16 + lq;
            const int coln = (i * 16 + lh * 4 + r) * 2;
            *(bf16_t*)(st + rowd * 128 + (coln ^ ((rowd & 7) << 4))) =
                (bf16_t)(acc[i][j][r] * s);
          }
    } else {
      const float sc = (which == 0) ? s * 0.125f * LOG2E : s;
      #pragma unroll
      for (int i = 0; i < 4; ++i)
        #pragma unroll
        for (int j = 0; j < 4; ++j)
          #pragma unroll
          for (int r = 0; r < 4; ++r) {
            const int row = i * 16 + lh * 4 + r;
            const int colb = (j * 16 + lq) * 2;
            *(bf16_t*)(st + row * 128 + (colb ^ ((row & 7) << 4))) =
                (bf16_t)(acc[i][j][r] * sc);
          }
    }
    __syncthreads();
    if (which == 2) {
      char* dstp = (char*)(VTb + ((size_t)(b * 12 + hh) * 64) * 1024 + nbase);
      #pragma unroll
      for (int it = 0; it < 8; ++it) {
        const int rowd = it * 8 + (l >> 3);
        const int coln = (l & 7) * 16;
        const u32x4 v = *(const u32x4*)(st + rowd * 128 + (coln ^ ((rowd & 7) << 4)));
        *(u32x4*)(dstp + rowd * 2048 + coln) = v;
      }
    } else {
      bf16_t* __restrict__ dst = (which == 0) ? Qb : Kb;
      char* dstp = (char*)(dst + ((size_t)(b * 12 + hh) * 1024 + nbase) * 64);
      #pragma unroll
      for (int it = 0; it < 8; ++it) {
        const int row = it * 8 + (l >> 3);
        const int colb = (l & 7) * 16;
        const u32x4 v = *(const u32x4*)(st + row * 128 + (colb ^ ((row & 7) << 4)));
        *(u32x4*)(dstp + row * 128 + colb) = v;
      }
    }
  } else {
    const int d0 = n0 + wn * 64;
    const float4 bv = *(const float4*)(bias + d0 + (l & 15) * 4);
    #pragma unroll
    for (int c = 0; c < 2; ++c) {
      #pragma unroll
      for (int i2 = 0; i2 < 2; ++i2) {
        const int i = c * 2 + i2;
        #pragma unroll
        for (int j = 0; j < 4; ++j)
          #pragma unroll
          for (int r = 0; r < 4; ++r) {
            const int row = i2 * 16 + lh * 4 + r;
            const int colb = (j * 16 + lq) * 4;
            *(float*)(st + row * 256 + (colb ^ ((row & 7) << 4))) = acc[i][j][r] * s;
          }
      }
      __syncthreads();
      #pragma unroll
      for (int it = 0; it < 8; ++it) {
        const int row = it * 4 + (l >> 4);
        const int colb = (l & 15) * 16;
        float4 v = *(const float4*)(st + row * 256 + (colb ^ ((row & 7) << 4)));
        v.x += bv.x; v.y += bv.y; v.z += bv.z; v.w += bv.w;
        *(float4*)((char*)(Out + (size_t)(mrow0 + c * 32 + row) * 768 + d0) + colb) = v;
      }
      __syncthreads();
    }
  }
}

// ---------- flash attention: LDS-free main loop (K/V L1/L2-resident) ----------
// Q pre-scaled by s*SCALE*log2e, K,V by s. Grid x=bh (XCD-affine), y=qb.
// 4 free-running waves x 32 q; K/V fragments loaded global->VGPR directly;
// no barriers, no staging, no main-loop bank conflicts. V loads issued
// before softmax so VALU hides their latency.
__global__ __launch_bounds__(256, 3) void k_attn(
    const bf16_t* __restrict__ Qb, const bf16_t* __restrict__ Kb,
    const bf16_t* __restrict__ VTb, bf16_t* __restrict__ Ob)
{
  __shared__ bf16_t eplds[4][2048];  // epilogue bounce only, 16 KiB
  const int t = threadIdx.x, l = t & 63, w = t >> 6;
  const int bh = blockIdx.x, qb = blockIdx.y;
  const int lq = l & 31, hi = l >> 5;
  const int q0 = qb * 128 + w * 32;

  const bf16_t* __restrict__ Kg = Kb + (size_t)bh * 65536;
  const bf16_t* __restrict__ Vg = VTb + (size_t)bh * 65536;

  bf16x8 qf[4];
  #pragma unroll
  for (int ks = 0; ks < 4; ++ks)
    qf[ks] = *(const bf16x8*)(Qb + (size_t)bh * 65536 + (q0 + lq) * 64 + ks * 16 + hi * 8);

  f32x16 ot0 = {}, ot1 = {};
  float mrun = -1e30f, lrun = 0.0f;

  for (int kt = 0; kt < 16; ++kt) {
    const int nn0 = kt * 64;

    // K fragments direct from L1/L2 (A-operand layout)
    const bf16_t* kp = Kg + (size_t)(nn0 + lq) * 64 + hi * 8;
    bf16x8 kf0[4], kf1[4];
    #pragma unroll
    for (int ks = 0; ks < 4; ++ks) kf0[ks] = *(const bf16x8*)(kp + ks * 16);
    #pragma unroll
    for (int ks = 0; ks < 4; ++ks) kf1[ks] = *(const bf16x8*)(kp + 2048 + ks * 16);

    f32x16 st0 = {}, st1 = {};
    __builtin_amdgcn_s_setprio(1);
    #pragma unroll
    for (int ks = 0; ks < 4; ++ks) {
      st0 = __builtin_amdgcn_mfma_f32_32x32x16_bf16(kf0[ks], qf[ks], st0, 0, 0, 0);
      st1 = __builtin_amdgcn_mfma_f32_32x32x16_bf16(kf1[ks], qf[ks], st1, 0, 0, 0);
    }
    __builtin_amdgcn_s_setprio(0);

    // V fragments issued now; softmax VALU hides their latency
    const bf16_t* vp = Vg + (size_t)lq * 1024 + nn0 + hi * 8;
    bf16x8 vf0[4], vf1[4];
    #pragma unroll
    for (int g = 0; g < 4; ++g) {
      vf0[g] = *(const bf16x8*)(vp + g * 16);
      vf1[g] = *(const bf16x8*)(vp + 32768 + g * 16);
    }

    // tree max over 32 in-lane values, then cross-half swap
    float m8[8];
    #pragma unroll
    for (int r = 0; r < 8; ++r)
      m8[r] = fmaxf(fmaxf(st0[r], st0[r + 8]), fmaxf(st1[r], st1[r + 8]));
    float pmax = fmaxf(fmaxf(fmaxf(m8[0], m8[1]), fmaxf(m8[2], m8[3])),
                       fmaxf(fmaxf(m8[4], m8[5]), fmaxf(m8[6], m8[7])));
    pmax = fmaxf(pmax, __shfl_xor(pmax, 32));

    // defer-max rescale (T13)
    if (__any(pmax > mrun + 8.0f)) {
      const float mn = fmaxf(mrun, pmax);
      const float corr = __builtin_amdgcn_exp2f(mrun - mn);
      lrun *= corr;
      #pragma unroll
      for (int r = 0; r < 16; ++r) { ot0[r] *= corr; ot1[r] *= corr; }
      mrun = mn;
    }

    float psum = 0.0f;
    __builtin_amdgcn_s_setprio(1);
    auto grp = [&](const f32x16& stv, int r0, const bf16x8& va, const bf16x8& vb) {
      float p[8];
      #pragma unroll
      for (int e = 0; e < 8; ++e) p[e] = __builtin_amdgcn_exp2f(stv[r0 + e] - mrun);
      psum += ((p[0] + p[1]) + (p[2] + p[3])) + ((p[4] + p[5]) + (p[6] + p[7]));
      const unsigned w0 = pk2(p[0], p[1]), w1 = pk2(p[2], p[3]);
      const unsigned w2 = pk2(p[4], p[5]), w3 = pk2(p[6], p[7]);
      const unsigned x0 = __shfl_xor(w0, 32), x1 = __shfl_xor(w1, 32);
      const unsigned x2 = __shfl_xor(w2, 32), x3 = __shfl_xor(w3, 32);
      const u32x4 fw = hi ? u32x4{x2, x3, w2, w3} : u32x4{w0, w1, x0, x1};
      const bf16x8 pf = __builtin_bit_cast(bf16x8, fw);
      ot0 = __builtin_amdgcn_mfma_f32_32x32x16_bf16(va, pf, ot0, 0, 0, 0);
      ot1 = __builtin_amdgcn_mfma_f32_32x32x16_bf16(vb, pf, ot1, 0, 0, 0);
    };
    grp(st0, 0, vf0[0], vf1[0]);
    grp(st0, 8, vf0[1], vf1[1]);
    grp(st1, 0, vf0[2], vf1[2]);
    grp(st1, 8, vf0[3], vf1[3]);
    __builtin_amdgcn_s_setprio(0);
    psum += __shfl_xor(psum, 32);
    lrun += psum;
  }

  // epilogue: O^T regs -> per-warp LDS (swizzled) -> coalesced stores
  bf16_t* olds = eplds[w];
  const float inv = 1.0f / lrun;
  #pragma unroll
  for (int dt = 0; dt < 2; ++dt)
    #pragma unroll
    for (int rg = 0; rg < 4; ++rg) {
      u16x4 pk;
      #pragma unroll
      for (int e = 0; e < 4; ++e)
        pk[e] = bf16bits((dt ? ot1[rg * 4 + e] : ot0[rg * 4 + e]) * inv);
      const int d = rg * 8 + hi * 4 + dt * 32;
      *(u16x4*)((char*)olds + ((lq * 128 + d * 2) ^ ((lq & 7) << 4))) = pk;
    }
  __syncthreads();  // order staging writes before vector readback (round-3 lesson)
  const int b = bh / 12, h = bh % 12;
  #pragma unroll
  for (int i = 0; i < 8; ++i) {
    const int q = i * 4 + (l >> 4);
    const u16x4 v =
        *(const u16x4*)((const char*)olds + ((q * 128 + (l & 15) * 8) ^ ((q & 7) << 4)));
    *(u16x4*)(Ob + ((size_t)(b * 1024 + q0 + q)) * 768 + h * 64 + (l & 15) * 4) = v;
  }
}

// ---------- launch ----------
extern "C" void kernel_launch(void* const* d_in, const int* in_sizes, int n_in,
                              void* d_out, int out_size, void* d_ws, size_t ws_size,
                              hipStream_t stream) {
  const float* x      = (const float*)d_in[0];
  const float* w_qkv  = (const float*)d_in[1];
  const float* w_proj = (const float*)d_in[2];
  const float* b_proj = (const float*)d_in[3];
  float* out = (float*)d_out;

  char* ws = (char*)d_ws;
  double* part  = (double*)ws;                    // 512 doubles
  double* scl   = (double*)(ws + 4096);           // 2 doubles
  bf16_t* xbf   = (bf16_t*)(ws + 4608);
  bf16_t* wqs   = (bf16_t*)(ws + 4608 + 25165824);
  bf16_t* wps   = (bf16_t*)(ws + 4608 + 25165824 + 3538944);
  bf16_t* qbuf  = (bf16_t*)(ws + 4608 + 25165824 + 3538944 + 1179648);
  bf16_t* kbuf  = qbuf + 12582912;
  bf16_t* vtbuf = kbuf + 12582912;
  bf16_t* aout  = xbf;  // x dead after GEMM1; alias attention output here

  k_abssum2<<<512, 256, 0, stream>>>(w_qkv, w_proj, part);
  k_reduce2<<<2, 256, 0, stream>>>(part, scl);
  k_prep<<<14592, 256, 0, stream>>>(w_qkv, w_proj, x, scl, wqs, wps, xbf);
  k_gemm<0><<<dim3(18, 64), 512, 0, stream>>>(xbf, wqs, scl, 1.0 / 1769472.0,
                                              qbuf, kbuf, vtbuf, nullptr, nullptr, 18);
  k_attn<<<dim3(192, 8), 256, 0, stream>>>(qbuf, kbuf, vtbuf, aout);
  k_gemm<1><<<dim3(6, 64), 512, 0, stream>>>(aout, wps, scl + 1, 1.0 / 589824.0,
                                             nullptr, nullptr, nullptr, b_proj, out, 6);
}